// Round 12
// baseline (420.804 us; speedup 1.0000x reference)
//
#include <hip/hip_runtime.h>
#include <math.h>

// CLIP transformer layer: B=8 S=1024 D=1024 H=16 DH=64 FF=4096, fp32 I/O,
// bf16 MFMA internals. Round 19: R18 build (412.5us) + QKV V-epilogue
// transposed through LDS. Old path: V cols stored as 8B bf16x4 at 2KB lane
// stride (d varies per lane) -> 64 L2 transactions per wave-store (~8x
// store cost over the 16MB V region) and V-blocks dominate QKV makespan.
// New path (V-blocks only, n0>=2048, whole-block uniform): after the
// K-loop the 96KB LDS is dead; write acc+bias into T[col][s] (stride 132),
// barrier, store d-rows of consecutive s -> coalesced. Everything else
// byte-identical to R18 (incl. the free gemm8<3> instantiation).

typedef __bf16 bf16_t;
typedef __bf16 bf16x4 __attribute__((ext_vector_type(4)));
typedef __bf16 bf16x8 __attribute__((ext_vector_type(8)));
typedef float f32x4 __attribute__((ext_vector_type(4)));

#define WAITVM(N) asm volatile("s_waitcnt vmcnt(" #N ")" ::: "memory")
#define WAITLGKM0 asm volatile("s_waitcnt lgkmcnt(0)" ::: "memory")
#define SCHEDBAR __builtin_amdgcn_sched_barrier(0)

// ---------------------------------------------------------------- helpers
__device__ __forceinline__ void async16(const void* g, void* l) {
    // global -> LDS direct DMA, 16B/lane. LDS dest is wave-uniform base + lane*16.
    __builtin_amdgcn_global_load_lds(
        (const __attribute__((address_space(1))) void*)g,
        (__attribute__((address_space(3))) void*)l,
        16, 0, 0);
}

__device__ __forceinline__ void ln_row(const float* __restrict__ x,
                                       const float* __restrict__ g,
                                       const float* __restrict__ bb,
                                       bf16_t* __restrict__ out, int row) {
    const int tid = threadIdx.x;
    const float4 xv = *(const float4*)(x + row * 1024 + tid * 4);
    float s1 = xv.x + xv.y + xv.z + xv.w;
    float s2 = xv.x * xv.x + xv.y * xv.y + xv.z * xv.z + xv.w * xv.w;
#pragma unroll
    for (int m = 32; m >= 1; m >>= 1) {
        s1 += __shfl_xor(s1, m);
        s2 += __shfl_xor(s2, m);
    }
    __shared__ float r1[4], r2[4];
    const int wid = tid >> 6, lane = tid & 63;
    if (lane == 0) { r1[wid] = s1; r2[wid] = s2; }
    __syncthreads();
    s1 = r1[0] + r1[1] + r1[2] + r1[3];
    s2 = r2[0] + r2[1] + r2[2] + r2[3];
    const float mu = s1 * (1.0f / 1024.0f);
    const float var = s2 * (1.0f / 1024.0f) - mu * mu;
    const float rs = rsqrtf(var + 1e-5f);
    const float4 gv = *(const float4*)(g + tid * 4);
    const float4 bv = *(const float4*)(bb + tid * 4);
    bf16x4 o;
    o[0] = (bf16_t)((xv.x - mu) * rs * gv.x + bv.x);
    o[1] = (bf16_t)((xv.y - mu) * rs * gv.y + bv.y);
    o[2] = (bf16_t)((xv.z - mu) * rs * gv.z + bv.z);
    o[3] = (bf16_t)((xv.w - mu) * rs * gv.w + bv.w);
    *(bf16x4*)(out + row * 1024 + tid * 4) = o;
}

// ---------------------------------------------------------------- prep: weight converts (blocks 0..12287) + LN1 (blocks 12288..20479)
__global__ __launch_bounds__(256) void prep(
    const float* __restrict__ s0, const float* __restrict__ s1,
    const float* __restrict__ s2, const float* __restrict__ s3,
    bf16_t* __restrict__ d0, bf16_t* __restrict__ d1,
    bf16_t* __restrict__ d2, bf16_t* __restrict__ d3,
    const float* __restrict__ x, const float* __restrict__ ln1g,
    const float* __restrict__ ln1b, bf16_t* __restrict__ h) {
    if (blockIdx.x >= 12288) {
        ln_row(x, ln1g, ln1b, h, blockIdx.x - 12288);
        return;
    }
    const int g = blockIdx.x * 256 + threadIdx.x;  // float4-group index
    const float* s;
    bf16_t* d;
    int off;
    if (g < 786432)       { s = s0; d = d0; off = g; }            // w_qkv 3M elem
    else if (g < 1048576) { s = s1; d = d1; off = g - 786432; }   // w_o 1M
    else if (g < 2097152) { s = s2; d = d2; off = g - 1048576; }  // w1 4M
    else                  { s = s3; d = d3; off = g - 2097152; }  // w2 4M
    const int i = off * 4;
    const float4 v = *(const float4*)(s + i);
    bf16x4 o;
    o[0] = (bf16_t)v.x; o[1] = (bf16_t)v.y; o[2] = (bf16_t)v.z; o[3] = (bf16_t)v.w;
    *(bf16x4*)(d + i) = o;
}

// ---------------------------------------------------------------- LayerNorm over bf16 input (x1 row of 1024) -> bf16
__global__ __launch_bounds__(256) void ln_b(const bf16_t* __restrict__ x,
                                            const float* __restrict__ g,
                                            const float* __restrict__ bb,
                                            bf16_t* __restrict__ out) {
    const int tid = threadIdx.x;
    const int row = blockIdx.x;
    const bf16x4 xb = *(const bf16x4*)(x + row * 1024 + tid * 4);
    const float x0 = (float)xb[0], x1 = (float)xb[1], x2 = (float)xb[2], x3 = (float)xb[3];
    float s1 = x0 + x1 + x2 + x3;
    float s2 = x0 * x0 + x1 * x1 + x2 * x2 + x3 * x3;
#pragma unroll
    for (int m = 32; m >= 1; m >>= 1) {
        s1 += __shfl_xor(s1, m);
        s2 += __shfl_xor(s2, m);
    }
    __shared__ float r1[4], r2[4];
    const int wid = tid >> 6, lane = tid & 63;
    if (lane == 0) { r1[wid] = s1; r2[wid] = s2; }
    __syncthreads();
    s1 = r1[0] + r1[1] + r1[2] + r1[3];
    s2 = r2[0] + r2[1] + r2[2] + r2[3];
    const float mu = s1 * (1.0f / 1024.0f);
    const float var = s2 * (1.0f / 1024.0f) - mu * mu;
    const float rs = rsqrtf(var + 1e-5f);
    const float4 gv = *(const float4*)(g + tid * 4);
    const float4 bv = *(const float4*)(bb + tid * 4);
    bf16x4 o;
    o[0] = (bf16_t)((x0 - mu) * rs * gv.x + bv.x);
    o[1] = (bf16_t)((x1 - mu) * rs * gv.y + bv.y);
    o[2] = (bf16_t)((x2 - mu) * rs * gv.z + bv.z);
    o[3] = (bf16_t)((x3 - mu) * rs * gv.w + bv.w);
    *(bf16x4*)(out + row * 1024 + tid * 4) = o;
}

// ---------------------------------------------------------------- gemm2p: 128x256 tile, 2-phase counted-vmcnt GEMM
// MODE 3: QKV (Q/K -> outb stride N, V-blocks -> LDS-transposed vt store);
// MODE 4: bias + fp32 resid -> bf16 (proj); MODE 5: bias + bf16 resid -> fp32 (FFN2).
template <int MODE>
__global__ __launch_bounds__(512, 2) void gemm2p(
    const bf16_t* __restrict__ A, const bf16_t* __restrict__ W,
    const float* __restrict__ bias, const float* __restrict__ residf,
    const bf16_t* __restrict__ residb,
    bf16_t* __restrict__ outb, float* __restrict__ outf,
    bf16_t* __restrict__ vt, int N, int K) {
    __shared__ bf16_t lds[49152];  // 96 KB
    const int tid = threadIdx.x;
    const int w = tid >> 6, lane = tid & 63;
    const int l15 = lane & 15, quad = lane >> 4;
    const int wm = (w & 1) * 64;  // M-offset within 128
    const int wc = w >> 1;        // N-quarter 0..3

    // XCD swizzle (nwg % 8 == 0), then groups of 8 m-blocks per n-column
    const int nwg = gridDim.x;
    const int wg = (blockIdx.x & 7) * (nwg >> 3) + (blockIdx.x >> 3);
    const int nbn = N >> 8;
    const int per = 8 * nbn;
    const int bm = (wg / per) * 8 + (wg % per) % 8;
    const int bn = (wg % per) / 8;
    const int m0 = bm << 7, n0 = bn << 8;

    // staging: A rows 0..127 (2 calls), B rows 0..255 (4 calls); 16B/thread.
    const bf16_t* pa[2]; const bf16_t* pb[4];
#pragma unroll
    for (int L = 0; L < 2; L++) {
        const int c = L * 512 + tid, r = c >> 3;
        pa[L] = A + (size_t)(m0 + r) * K + ((c & 7) ^ (r & 7)) * 8;
    }
#pragma unroll
    for (int L = 0; L < 4; L++) {
        const int c = L * 512 + tid, r = c >> 3;
        pb[L] = W + (size_t)(n0 + r) * K + ((c & 7) ^ (r & 7)) * 8;
    }

    // fragment base pointers (row&7 == l15&7 -> wave-invariant swizzle)
    const int swz0 = (quad ^ (l15 & 7)) * 8;
    const int swz1 = ((4 + quad) ^ (l15 & 7)) * 8;
    const int fragoffA = wm * 64 + l15 * 64 + swz0;
    const bf16_t* bA0 = lds + fragoffA;
    const bf16_t* bA1 = lds + wm * 64 + l15 * 64 + swz1;
    const bf16_t* bB0 = lds + 8192 + wc * 2048 + l15 * 64 + swz0;
    const bf16_t* bB1 = lds + 8192 + wc * 2048 + l15 * 64 + swz1;
    const bf16_t* cA0 = bA0 + 24576;  // twin-buffer pointers
    const bf16_t* cA1 = bA1 + 24576;
    const bf16_t* cB0 = bB0 + 24576;
    const bf16_t* cB1 = bB1 + 24576;

    f32x4 acc[4][4] = {};
    bf16x8 af[4][2], bfr[4][2];

    // prologue: stage tile 0 (A, B-lo, B-hi); publish A+B-lo
    async16(pa[0], lds + w * 512);
    async16(pa[1], lds + 4096 + w * 512);
    async16(pb[0], lds + 8192 + w * 512);
    async16(pb[1], lds + 12288 + w * 512);
    async16(pb[2], lds + 16384 + w * 512);
    async16(pb[3], lds + 20480 + w * 512);
    WAITVM(2);
    __builtin_amdgcn_s_barrier();

    const int NT = K >> 6;
    for (int t = 0; t < NT - 1; ++t) {
        bf16_t* nb = (bf16_t*)(cA0 - fragoffA);  // twin (not-being-read) buffer
        const int kn = (t + 1) << 6;

        // ---- P1: read A + B-lo frags; stage A(t+1) + B-lo(t+1)
#pragma unroll
        for (int i = 0; i < 4; i++) {
            af[i][0] = *(const bf16x8*)(bA0 + i * 1024);
            af[i][1] = *(const bf16x8*)(bA1 + i * 1024);
        }
#pragma unroll
        for (int j = 0; j < 2; j++) {
            bfr[j][0] = *(const bf16x8*)(bB0 + j * 1024);
            bfr[j][1] = *(const bf16x8*)(bB1 + j * 1024);
        }
        async16(pa[0] + kn, nb + w * 512);
        async16(pa[1] + kn, nb + 4096 + w * 512);
        async16(pb[0] + kn, nb + 8192 + w * 512);
        async16(pb[1] + kn, nb + 12288 + w * 512);
        SCHEDBAR;
        __builtin_amdgcn_s_barrier();
        WAITLGKM0;
        SCHEDBAR;
        __builtin_amdgcn_s_setprio(1);
#pragma unroll
        for (int i = 0; i < 4; i++)
#pragma unroll
            for (int j = 0; j < 2; j++)
#pragma unroll
                for (int f = 0; f < 2; f++)
                    acc[i][j] = __builtin_amdgcn_mfma_f32_16x16x32_bf16(af[i][f], bfr[j][f], acc[i][j], 0, 0, 0);
        __builtin_amdgcn_s_setprio(0);
        SCHEDBAR;
        WAITVM(4);  // publish B-hi(t) for P2
        __builtin_amdgcn_s_barrier();

        // ---- P2: read B-hi frags; stage B-hi(t+1)
#pragma unroll
        for (int j = 2; j < 4; j++) {
            bfr[j][0] = *(const bf16x8*)(bB0 + 8192 + (j & 1) * 1024);
            bfr[j][1] = *(const bf16x8*)(bB1 + 8192 + (j & 1) * 1024);
        }
        async16(pb[2] + kn, nb + 16384 + w * 512);
        async16(pb[3] + kn, nb + 20480 + w * 512);
        SCHEDBAR;
        __builtin_amdgcn_s_barrier();
        WAITLGKM0;
        SCHEDBAR;
        __builtin_amdgcn_s_setprio(1);
#pragma unroll
        for (int i = 0; i < 4; i++)
#pragma unroll
            for (int j = 2; j < 4; j++)
#pragma unroll
                for (int f = 0; f < 2; f++)
                    acc[i][j] = __builtin_amdgcn_mfma_f32_16x16x32_bf16(af[i][f], bfr[j][f], acc[i][j], 0, 0, 0);
        __builtin_amdgcn_s_setprio(0);
        SCHEDBAR;
        WAITVM(2);  // publish A(t+1) + B-lo(t+1) for next P1
        __builtin_amdgcn_s_barrier();

        // swap buffer base pointers
        { const bf16_t* s;
          s = bA0; bA0 = cA0; cA0 = s;
          s = bA1; bA1 = cA1; cA1 = s;
          s = bB0; bB0 = cB0; cB0 = s;
          s = bB1; bB1 = cB1; cB1 = s; }
    }

    // peeled last tile: drain 0, no staging
    {
        // P1
#pragma unroll
        for (int i = 0; i < 4; i++) {
            af[i][0] = *(const bf16x8*)(bA0 + i * 1024);
            af[i][1] = *(const bf16x8*)(bA1 + i * 1024);
        }
#pragma unroll
        for (int j = 0; j < 2; j++) {
            bfr[j][0] = *(const bf16x8*)(bB0 + j * 1024);
            bfr[j][1] = *(const bf16x8*)(bB1 + j * 1024);
        }
        SCHEDBAR;
        __builtin_amdgcn_s_barrier();
        WAITLGKM0;
        SCHEDBAR;
        __builtin_amdgcn_s_setprio(1);
#pragma unroll
        for (int i = 0; i < 4; i++)
#pragma unroll
            for (int j = 0; j < 2; j++)
#pragma unroll
                for (int f = 0; f < 2; f++)
                    acc[i][j] = __builtin_amdgcn_mfma_f32_16x16x32_bf16(af[i][f], bfr[j][f], acc[i][j], 0, 0, 0);
        __builtin_amdgcn_s_setprio(0);
        SCHEDBAR;
        WAITVM(0);  // publish B-hi(last)
        __builtin_amdgcn_s_barrier();
        // P2
#pragma unroll
        for (int j = 2; j < 4; j++) {
            bfr[j][0] = *(const bf16x8*)(bB0 + 8192 + (j & 1) * 1024);
            bfr[j][1] = *(const bf16x8*)(bB1 + 8192 + (j & 1) * 1024);
        }
        WAITLGKM0;
        SCHEDBAR;
        __builtin_amdgcn_s_setprio(1);
#pragma unroll
        for (int i = 0; i < 4; i++)
#pragma unroll
            for (int j = 2; j < 4; j++)
#pragma unroll
                for (int f = 0; f < 2; f++)
                    acc[i][j] = __builtin_amdgcn_mfma_f32_16x16x32_bf16(af[i][f], bfr[j][f], acc[i][j], 0, 0, 0);
        __builtin_amdgcn_s_setprio(0);
    }

    // -------- V-block epilogue (MODE 3, n0 >= 2048): LDS transpose --------
    // Block = 4 bh-groups x 64 d x 128 s. Write acc+bias into T[c][s]
    // (stride 132, bank-spread), barrier, then store d-rows of 64
    // consecutive s per thread-half -> coalesced global writes.
    if (MODE == 3 && n0 >= 2048) {
        bf16_t* T = lds;  // K-loop LDS is dead; 256*132*2B = 67.6KB < 96KB
        __syncthreads();  // all waves done with frag reads
#pragma unroll
        for (int i = 0; i < 4; i++) {
            const int s = wm + i * 16 + quad * 4;  // local row 0..127
#pragma unroll
            for (int j = 0; j < 4; j++) {
                const int c = (j >> 1) * 128 + wc * 32 + (j & 1) * 16 + l15;
                const float bcol = bias[n0 + c];
                bf16x4 pk;
#pragma unroll
                for (int q = 0; q < 4; q++) pk[q] = (bf16_t)(acc[i][j][q] + bcol);
                *(bf16x4*)(T + c * 132 + s) = pk;
            }
        }
        __syncthreads();
        const int c = tid >> 1, sh = (tid & 1) * 64;  // col 0..255, s-half
        const int bh = (m0 >> 10) * 16 + ((n0 - 2048) >> 6) + (c >> 6);
        const int d = c & 63;
        bf16_t* dst = vt + (size_t)bh * 65536 + d * 1024 + (m0 & 1023) + sh;
        const bf16_t* src = T + c * 132 + sh;
#pragma unroll
        for (int k = 0; k < 64; k += 4)
            *(bf16x4*)(dst + k) = *(const bf16x4*)(src + k);
        return;
    }

    // epilogue: C/D layout col=lane&15 (n), row=(lane>>4)*4+reg (m)
#pragma unroll
    for (int i = 0; i < 4; i++) {
        const int row0 = m0 + wm + i * 16 + quad * 4;
#pragma unroll
        for (int j = 0; j < 4; j++) {
            const int col = n0 + (j >> 1) * 128 + wc * 32 + (j & 1) * 16 + l15;
            const float bcol = bias[col];
            if (MODE == 4) {        // + fp32 resid -> bf16 out
#pragma unroll
                for (int q = 0; q < 4; q++) {
                    const size_t idx = (size_t)(row0 + q) * N + col;
                    outb[idx] = (bf16_t)(acc[i][j][q] + bcol + residf[idx]);
                }
            } else if (MODE == 5) { // + bf16 resid -> fp32 out
#pragma unroll
                for (int q = 0; q < 4; q++) {
                    const size_t idx = (size_t)(row0 + q) * N + col;
                    outf[idx] = acc[i][j][q] + bcol + (float)residb[idx];
                }
            } else {                // MODE 3 Q/K columns (V handled above)
#pragma unroll
                for (int q = 0; q < 4; q++)
                    outb[(size_t)(row0 + q) * N + col] = (bf16_t)(acc[i][j][q] + bcol);
            }
        }
    }
}

// ---------------------------------------------------------------- 256x256 8-phase GEMM, counted vmcnt (round-13, best measured)
// MODE 1: bias+gelu -> bf16 (FFN1); MODE 3 instantiated (not launched) to
// preserve the R13/R15 codegen context in which MODE 1 compiles fast.
template <int MODE>
__global__ __launch_bounds__(512, 2) void gemm8(
    const bf16_t* __restrict__ A, const bf16_t* __restrict__ W,
    const float* __restrict__ bias, bf16_t* __restrict__ outb,
    bf16_t* __restrict__ vt, int N, int K) {
    __shared__ bf16_t lds[65536];  // 128 KB
    const int tid = threadIdx.x;
    const int w = tid >> 6, lane = tid & 63;
    const int l15 = lane & 15, quad = lane >> 4;
    const int wr = w >> 2, wc = w & 3;

    const int nwg = gridDim.x;
    const int wg = (blockIdx.x & 7) * (nwg >> 3) + (blockIdx.x >> 3);
    const int nbn = N >> 8;
    const int per = 8 * nbn;
    const int bm = (wg / per) * 8 + (wg % per) % 8;
    const int bn = (wg % per) / 8;
    const int m0 = bm << 8, n0 = bn << 8;

    int r_[2], s_[2];
#pragma unroll
    for (int L = 0; L < 2; L++) {
        const int c = L * 512 + tid;
        r_[L] = c >> 3;
        s_[L] = ((c & 7) ^ (r_[L] & 7)) * 8;
    }
    const bf16_t* pa0[2]; const bf16_t* pa1[2];
    const bf16_t* pb0[2]; const bf16_t* pb1[2];
#pragma unroll
    for (int L = 0; L < 2; L++) {
        pa0[L] = A + (size_t)(m0 + r_[L]) * K + s_[L];
        pa1[L] = pa0[L] + (size_t)128 * K;
        pb0[L] = W + (size_t)(n0 + r_[L]) * K + s_[L];
        pb1[L] = pb0[L] + (size_t)128 * K;
    }

    const int fragoff = wr * 4096 + l15 * 64;
    const int swz0 = (quad ^ (l15 & 7)) * 8;
    const int swz1 = ((4 + quad) ^ (l15 & 7)) * 8;
    const bf16_t* bA0 = lds + fragoff + swz0;
    const bf16_t* bA1 = lds + fragoff + swz1;
    const bf16_t* bB0 = lds + 16384 + wc * 2048 + l15 * 64 + swz0;
    const bf16_t* bB1 = lds + 16384 + wc * 2048 + l15 * 64 + swz1;
    const bf16_t* cA0 = bA0 + 32768;
    const bf16_t* cA1 = bA1 + 32768;
    const bf16_t* cB0 = bB0 + 32768;
    const bf16_t* cB1 = bB1 + 32768;

    f32x4 acc[8][4] = {};
    bf16x8 af[4][2], bfr[4][2];

    // prologue: stage tile 0 into buf 0 (A-lo, B-lo, B-hi, A-hi);
    // counted wait publishes A-lo+B-lo; B-hi/A-hi stay in flight.
    async16(pa0[0], lds + w * 512);
    async16(pa0[1], lds + 4096 + w * 512);
    async16(pb0[0], lds + 16384 + w * 512);
    async16(pb0[1], lds + 20480 + w * 512);
    async16(pb1[0], lds + 24576 + w * 512);
    async16(pb1[1], lds + 28672 + w * 512);
    async16(pa1[0], lds + 8192 + w * 512);
    async16(pa1[1], lds + 12288 + w * 512);
    WAITVM(4);
    __builtin_amdgcn_s_barrier();

    const int NT = K >> 6;
    for (int t = 0; t < NT - 1; ++t) {
        bf16_t* nb = (bf16_t*)(cA0 - (fragoff + swz0));  // twin buffer
        const int kn = (t + 1) << 6;

        // ---- P1: read af-lo + bf-lo; stage A-lo(t+1)
#pragma unroll
        for (int i = 0; i < 4; i++) {
            af[i][0] = *(const bf16x8*)(bA0 + i * 1024);
            af[i][1] = *(const bf16x8*)(bA1 + i * 1024);
        }
#pragma unroll
        for (int j = 0; j < 2; j++) {
            bfr[j][0] = *(const bf16x8*)(bB0 + j * 1024);
            bfr[j][1] = *(const bf16x8*)(bB1 + j * 1024);
        }
        async16(pa0[0] + kn, nb + w * 512);
        async16(pa0[1] + kn, nb + 4096 + w * 512);
        SCHEDBAR;
        __builtin_amdgcn_s_barrier();
        WAITLGKM0;
        SCHEDBAR;
        __builtin_amdgcn_s_setprio(1);
#pragma unroll
        for (int i = 0; i < 4; i++)
#pragma unroll
            for (int j = 0; j < 2; j++)
#pragma unroll
                for (int f = 0; f < 2; f++)
                    acc[i][j] = __builtin_amdgcn_mfma_f32_16x16x32_bf16(af[i][f], bfr[j][f], acc[i][j], 0, 0, 0);
        __builtin_amdgcn_s_setprio(0);
        SCHEDBAR;
        WAITVM(4);  // publish B-hi(t) for P2
        __builtin_amdgcn_s_barrier();

        // ---- P2: read bf-hi; stage B-lo(t+1)
#pragma unroll
        for (int j = 2; j < 4; j++) {
            bfr[j][0] = *(const bf16x8*)(bB0 + 8192 + (j & 1) * 1024);
            bfr[j][1] = *(const bf16x8*)(bB1 + 8192 + (j & 1) * 1024);
        }
        async16(pb0[0] + kn, nb + 16384 + w * 512);
        async16(pb0[1] + kn, nb + 20480 + w * 512);
        SCHEDBAR;
        __builtin_amdgcn_s_barrier();
        WAITLGKM0;
        SCHEDBAR;
        __builtin_amdgcn_s_setprio(1);
#pragma unroll
        for (int i = 0; i < 4; i++)
#pragma unroll
            for (int j = 2; j < 4; j++)
#pragma unroll
                for (int f = 0; f < 2; f++)
                    acc[i][j] = __builtin_amdgcn_mfma_f32_16x16x32_bf16(af[i][f], bfr[j][f], acc[i][j], 0, 0, 0);
        __builtin_amdgcn_s_setprio(0);
        SCHEDBAR;
        WAITVM(4);  // publish A-hi(t) for P3
        __builtin_amdgcn_s_barrier();

        // ---- P3: read af-hi; stage B-hi(t+1)
#pragma unroll
        for (int i = 0; i < 4; i++) {
            af[i][0] = *(const bf16x8*)(bA0 + 8192 + i * 1024);
            af[i][1] = *(const bf16x8*)(bA1 + 8192 + i * 1024);
        }
        async16(pb1[0] + kn, nb + 24576 + w * 512);
        async16(pb1[1] + kn, nb + 28672 + w * 512);
        SCHEDBAR;
        __builtin_amdgcn_s_barrier();
        WAITLGKM0;
        SCHEDBAR;
        __builtin_amdgcn_s_setprio(1);
#pragma unroll
        for (int i = 0; i < 4; i++)
#pragma unroll
            for (int j = 0; j < 2; j++)
#pragma unroll
                for (int f = 0; f < 2; f++)
                    acc[i + 4][j] = __builtin_amdgcn_mfma_f32_16x16x32_bf16(af[i][f], bfr[j][f], acc[i + 4][j], 0, 0, 0);
        __builtin_amdgcn_s_setprio(0);
        SCHEDBAR;
        __builtin_amdgcn_s_barrier();  // no wait: P4 reads nothing

        // ---- P4: stage A-hi(t+1); MFMA; publish A-lo,B-lo(t+1)
        async16(pa1[0] + kn, nb + 8192 + w * 512);
        async16(pa1[1] + kn, nb + 12288 + w * 512);
        SCHEDBAR;
        __builtin_amdgcn_s_setprio(1);
#pragma unroll
        for (int i = 0; i < 4; i++)
#pragma unroll
            for (int j = 2; j < 4; j++)
#pragma unroll
                for (int f = 0; f < 2; f++)
                    acc[i + 4][j] = __builtin_amdgcn_mfma_f32_16x16x32_bf16(af[i][f], bfr[j][f], acc[i + 4][j], 0, 0, 0);
        __builtin_amdgcn_s_setprio(0);
        SCHEDBAR;
        WAITVM(4);  // publish A-lo,B-lo(t+1) for next P1
        __builtin_amdgcn_s_barrier();

        // swap buffer base pointers
        { const bf16_t* s;
          s = bA0; bA0 = cA0; cA0 = s;
          s = bA1; bA1 = cA1; cA1 = s;
          s = bB0; bB0 = cB0; cB0 = s;
          s = bB1; bB1 = cB1; cB1 = s; }
    }

    // peeled last tile: waits drain 2 -> 0, no staging
    {
        // P1
#pragma unroll
        for (int i = 0; i < 4; i++) {
            af[i][0] = *(const bf16x8*)(bA0 + i * 1024);
            af[i][1] = *(const bf16x8*)(bA1 + i * 1024);
        }
#pragma unroll
        for (int j = 0; j < 2; j++) {
            bfr[j][0] = *(const bf16x8*)(bB0 + j * 1024);
            bfr[j][1] = *(const bf16x8*)(bB1 + j * 1024);
        }
        SCHEDBAR;
        __builtin_amdgcn_s_barrier();
        WAITLGKM0;
        SCHEDBAR;
        __builtin_amdgcn_s_setprio(1);
#pragma unroll
        for (int i = 0; i < 4; i++)
#pragma unroll
            for (int j = 0; j < 2; j++)
#pragma unroll
                for (int f = 0; f < 2; f++)
                    acc[i][j] = __builtin_amdgcn_mfma_f32_16x16x32_bf16(af[i][f], bfr[j][f], acc[i][j], 0, 0, 0);
        __builtin_amdgcn_s_setprio(0);
        SCHEDBAR;
        WAITVM(2);  // publish B-hi(last)
        __builtin_amdgcn_s_barrier();
        // P2
#pragma unroll
        for (int j = 2; j < 4; j++) {
            bfr[j][0] = *(const bf16x8*)(bB0 + 8192 + (j & 1) * 1024);
            bfr[j][1] = *(const bf16x8*)(bB1 + 8192 + (j & 1) * 1024);
        }
        SCHEDBAR;
        __builtin_amdgcn_s_barrier();
        WAITLGKM0;
        SCHEDBAR;
        __builtin_amdgcn_s_setprio(1);
#pragma unroll
        for (int i = 0; i < 4; i++)
#pragma unroll
            for (int j = 2; j < 4; j++)
#pragma unroll
                for (int f = 0; f < 2; f++)
                    acc[i][j] = __builtin_amdgcn_mfma_f32_16x16x32_bf16(af[i][f], bfr[j][f], acc[i][j], 0, 0, 0);
        __builtin_amdgcn_s_setprio(0);
        SCHEDBAR;
        WAITVM(0);  // publish A-hi(last)
        __builtin_amdgcn_s_barrier();
        // P3 + P4
#pragma unroll
        for (int i = 0; i < 4; i++) {
            af[i][0] = *(const bf16x8*)(bA0 + 8192 + i * 1024);
            af[i][1] = *(const bf16x8*)(bA1 + 8192 + i * 1024);
        }
        WAITLGKM0;
        SCHEDBAR;
        __builtin_amdgcn_s_setprio(1);
#pragma unroll
        for (int i = 0; i < 4; i++)
#pragma unroll
            for (int j = 0; j < 4; j++)
#pragma unroll
                for (int f = 0; f < 2; f++)
                    acc[i + 4][j] = __builtin_amdgcn_mfma_f32_16x16x32_bf16(af[i][f], bfr[j][f], acc[i + 4][j], 0, 0, 0);
        __builtin_amdgcn_s_setprio(0);
    }

    // epilogue
#pragma unroll
    for (int i = 0; i < 8; i++) {
        const int row0 = m0 + (i >> 2) * 128 + wr * 64 + (i & 3) * 16 + quad * 4;
#pragma unroll
        for (int j = 0; j < 4; j++) {
            const int col = n0 + (j >> 1) * 128 + wc * 32 + (j & 1) * 16 + l15;
            const float bcol = bias[col];
            float v4[4];
#pragma unroll
            for (int q = 0; q < 4; q++) {
                float v = acc[i][j][q] + bcol;
                if (MODE == 1) {  // tanh-GELU == x * sigmoid(2u)
                    const float u2 = -1.5957691216057308f * (v + 0.044715f * v * v * v);
                    v = v * __builtin_amdgcn_rcpf(1.0f + __expf(u2));
                }
                v4[q] = v;
            }
            if (MODE == 3 && col >= 2048) {
                const int bh = (row0 >> 10) * 16 + ((col - 2048) >> 6);
                const int d = (col - 2048) & 63;
                bf16x4 pk;
#pragma unroll
                for (int q = 0; q < 4; q++) pk[q] = (bf16_t)v4[q];
                *(bf16x4*)(vt + (size_t)bh * 65536 + d * 1024 + (row0 & 1023)) = pk;
            } else {
#pragma unroll
                for (int q = 0; q < 4; q++)
                    outb[(size_t)(row0 + q) * N + col] = (bf16_t)v4[q];
            }
        }
    }
}

// Explicit instantiation of gemm8<3> (never launched): preserves the
// R13/R15 module codegen context for gemm8<1>. Rule #19.
template __global__ void gemm8<3>(const bf16_t*, const bf16_t*, const float*,
                                  bf16_t*, bf16_t*, int, int);

// ---------------------------------------------------------------- MFMA causal flash attention, K/V double-buffered, balanced grid
// 512 1-D blocks, 512 thr = 8 waves; wave owns 32 queries (two 16-q groups).
// Complementary-qb pairing: beta<256 -> (qb=beta&3, bh=beta>>2); beta>=256
// -> (qb=3-(beta-256)&3, bh=64+(beta-256)>>2). Blocks beta and beta+256
// land on the same CU (round-robin) and their causal work sums to a
// constant 20 tile-units. bh-locality preserved.
__global__ __launch_bounds__(512) void attn_mfma(const bf16_t* __restrict__ qkv,
                                                 const bf16_t* __restrict__ vt,
                                                 bf16_t* __restrict__ o) {
    __shared__ bf16_t Ks[2][4096];    // [buf][key=64][dseg swizzled] 16KB
    __shared__ bf16_t Vs[2][4096];    // [buf][d=64][kseg swizzled]   16KB
    __shared__ bf16_t Ps[8][16][72];  // per-wave P[q(16)][key], pad 72 (18KB)
    const int tid = threadIdx.x;
    const int w = tid >> 6;           // 0..7
    const int lane = tid & 63;
    const int l15 = lane & 15;
    const int quad = lane >> 4;
    const int beta = blockIdx.x;      // 0..511
    int qb, bh;
    if (beta < 256) { qb = beta & 3; bh = beta >> 2; }
    else { const int gm = beta - 256; qb = 3 - (gm & 3); bh = 64 + (gm >> 2); }
    const int b = bh >> 4, h = bh & 15;

    const int qrow = b * 1024 + qb * 256 + w * 32;  // wave's first query row (global)

    // Q^T B-frags for both 16-q groups, scaled by 1/8 (exact pow2)
    bf16x8 qf[2][2];
#pragma unroll
    for (int g = 0; g < 2; g++)
#pragma unroll
        for (int f = 0; f < 2; f++) {
            bf16x8 t = *(const bf16x8*)(qkv + (size_t)(qrow + g * 16 + l15) * 3072 + h * 64 + f * 32 + quad * 8);
#pragma unroll
            for (int e = 0; e < 8; e++) t[e] = (bf16_t)((float)t[e] * 0.125f);
            qf[g][f] = t;
        }

    f32x4 Ot[2][4] = {};
    float mrow[2] = {-3.0e38f, -3.0e38f};
    float lrow[2] = {0.0f, 0.0f};

    // staging: 1 call/wave per operand; chunk c = w*64 + lane (16B each)
    const int c0 = w * 64 + lane;
    const int r0 = c0 >> 3, g0 = (((c0 & 7) ^ (r0 & 7))) * 8;

    const bf16_t* kbase = qkv + (size_t)(b * 1024) * 3072 + 1024 + h * 64;
    const bf16_t* vbase = vt + (size_t)bh * 64 * 1024;

    const int ktmax = 4 * qb + 3;  // keys up to qb*256+255

    // prologue: stage tile 0 into buf 0, full publish
    async16(kbase + (size_t)r0 * 3072 + g0, &Ks[0][0] + w * 512);
    async16(vbase + (size_t)r0 * 1024 + g0, &Vs[0][0] + w * 512);
    WAITVM(0);
    __builtin_amdgcn_s_barrier();

    int p = 0;
    for (int kt = 0; kt <= ktmax; kt++, p ^= 1) {
        // issue-early: stage tile kt+1 into the twin buffer (race-free:
        // its last reads finished before the previous iteration's barrier)
        if (kt < ktmax) {
            async16(kbase + (size_t)((kt + 1) * 64 + r0) * 3072 + g0, &Ks[p ^ 1][0] + w * 512);
            async16(vbase + (size_t)r0 * 1024 + (kt + 1) * 64 + g0, &Vs[p ^ 1][0] + w * 512);
        }
        const bf16_t* Kp = &Ks[p][0];
        const bf16_t* Vp = &Vs[p][0];

#pragma unroll
        for (int g = 0; g < 2; g++) {
            const int qmaxw = qb * 256 + w * 32 + g * 16 + 15;  // group's max query
            if (kt * 64 > qmaxw) continue;  // whole tile masked for this group
            const int ktd = qmaxw >> 6;     // diagonal tile
            const int kbd = (2 * w + g) & 3;

            f32x4 sf[4];
#pragma unroll
            for (int kb = 0; kb < 4; kb++) {
                if (kt * 64 + kb * 16 > qmaxw) {  // fully masked key-block
                    sf[kb] = (f32x4){-3.0e38f, -3.0e38f, -3.0e38f, -3.0e38f};
                    continue;
                }
                const int r = kb * 16 + l15;
                f32x4 acc = {};
#pragma unroll
                for (int f = 0; f < 2; f++) {
                    const int seg = (f * 4 + quad) ^ (r & 7);
                    const bf16x8 kf = *(const bf16x8*)(Kp + r * 64 + seg * 8);
                    acc = __builtin_amdgcn_mfma_f32_16x16x32_bf16(kf, qf[g][f], acc, 0, 0, 0);
                }
                if (kt == ktd && kb == kbd) {  // diagonal 16-block: per-element mask
#pragma unroll
                    for (int rr2 = 0; rr2 < 4; rr2++)
                        if (quad * 4 + rr2 > l15) acc[rr2] = -3.0e38f;
                }
                sf[kb] = acc;
            }

            // online softmax over columns (q = l15)
            float tmax = -3.0e38f;
#pragma unroll
            for (int kb = 0; kb < 4; kb++)
#pragma unroll
                for (int rr2 = 0; rr2 < 4; rr2++) tmax = fmaxf(tmax, sf[kb][rr2]);
            tmax = fmaxf(tmax, __shfl_xor(tmax, 16));
            tmax = fmaxf(tmax, __shfl_xor(tmax, 32));
            const float mnew = fmaxf(mrow[g], tmax);
            const float alpha = __expf(mrow[g] - mnew);
            float psum = 0.0f;
#pragma unroll
            for (int kb = 0; kb < 4; kb++) {
                bf16x4 pk;
#pragma unroll
                for (int rr2 = 0; rr2 < 4; rr2++) {
                    const float p2 = __expf(sf[kb][rr2] - mnew);
                    psum += p2;
                    pk[rr2] = (bf16_t)p2;
                }
                *(bf16x4*)(&Ps[w][l15][kb * 16 + quad * 4]) = pk;
            }
            psum += __shfl_xor(psum, 16);
            psum += __shfl_xor(psum, 32);
            lrow[g] = lrow[g] * alpha + psum;
            mrow[g] = mnew;
#pragma unroll
            for (int db = 0; db < 4; db++)
#pragma unroll
                for (int rr2 = 0; rr2 < 4; rr2++) Ot[g][db][rr2] *= alpha;

#pragma unroll
            for (int ks = 0; ks < 2; ks++) {
                if (kt * 64 + ks * 32 > qmaxw) break;  // all-zero P (wave-uniform)
                const bf16x8 pf = *(const bf16x8*)(&Ps[w][l15][ks * 32 + quad * 8]);
#pragma unroll
                for (int db = 0; db < 4; db++) {
                    const int d = db * 16 + l15;
                    const int seg = (ks * 4 + quad) ^ (d & 7);
                    const bf16x8 vf = *(const bf16x8*)(Vp + d * 64 + seg * 8);
                    Ot[g][db] = __builtin_amdgcn_mfma_f32_16x16x32_bf16(vf, pf, Ot[g][db], 0, 0, 0);
                }
            }
        }
        SCHEDBAR;
        WAITVM(0);  // kt+1's loads issued before compute: drain ~free
        __builtin_amdgcn_s_barrier();
    }

#pragma unroll
    for (int g = 0; g < 2; g++) {
        const float rl = 1.0f / lrow[g];
#pragma unroll
        for (int db = 0; db < 4; db++) {
            bf16x4 ov;
#pragma unroll
            for (int rr2 = 0; rr2 < 4; rr2++) ov[rr2] = (bf16_t)(Ot[g][db][rr2] * rl);
            *(bf16x4*)(o + (size_t)(qrow + g * 16 + l15) * 1024 + h * 64 + db * 16 + quad * 4) = ov;
        }
    }
}

// ---------------------------------------------------------------- launch
extern "C" void kernel_launch(void* const* d_in, const int* in_sizes, int n_in,
                              void* d_out, int out_size, void* d_ws, size_t ws_size,
                              hipStream_t stream) {
    const float* x     = (const float*)d_in[0];
    const float* ln1g  = (const float*)d_in[1];
    const float* ln1b  = (const float*)d_in[2];
    const float* w_qkv = (const float*)d_in[3];
    const float* b_qkv = (const float*)d_in[4];
    const float* w_o   = (const float*)d_in[5];
    const float* b_o   = (const float*)d_in[6];
    const float* ln2g  = (const float*)d_in[7];
    const float* ln2b  = (const float*)d_in[8];
    const float* w1    = (const float*)d_in[9];
    const float* b1    = (const float*)d_in[10];
    const float* w2    = (const float*)d_in[11];
    const float* b2    = (const float*)d_in[12];
    float* out = (float*)d_out;

    char* w = (char*)d_ws;
    bf16_t* wbqkv = (bf16_t*)(w + 0);          //  6 MB  [3072,1024] bf16
    bf16_t* wbo   = (bf16_t*)(w + 6291456);    //  2 MB  [1024,1024]
    bf16_t* wb1   = (bf16_t*)(w + 8388608);    //  8 MB  [4096,1024]
    bf16_t* wb2   = (bf16_t*)(w + 16777216);   //  8 MB  [1024,4096]
    bf16_t* h     = (bf16_t*)(w + 25165824);   // 16 MB  [8192,1024] (LN1/LN2 out)
    bf16_t* qkv   = (bf16_t*)(w + 41943040);   // 48 MB  [8192,3072] (V region unused)
    bf16_t* ob    = (bf16_t*)(w + 92274688);   // 16 MB  [8192,1024]
    bf16_t* x1b   = (bf16_t*)(w + 109051904);  // 16 MB  [8192,1024] bf16 residual stream
    bf16_t* f     = (bf16_t*)(w + 142606336);  // 64 MB  [8192,4096] (FFN1 out)
    bf16_t* vtb   = (bf16_t*)(w + 142606336);  // 16 MB  [128][64][1024] (aliases f; dead before FFN1)

    // weight converts + LN1 in one dispatch
    prep<<<20480, 256, 0, stream>>>(w_qkv, w_o, w1, w2, wbqkv, wbo, wb1, wb2,
                                    x, ln1g, ln1b, h);
    // QKV: 128x256 2-phase counted-vmcnt, 768 blocks = 3 exact rounds
    gemm2p<3><<<768, 512, 0, stream>>>(h, wbqkv, b_qkv, nullptr, nullptr, qkv, nullptr, vtb, 3072, 1024);
    // attention: balanced 1-D grid (complementary-qb pairing)
    attn_mfma<<<512, 512, 0, stream>>>(qkv, vtb, ob);
    // proj: x1b = bf16(x + ob @ w_o^T + b_o)
    gemm2p<4><<<256, 512, 0, stream>>>(ob, wbo, b_o, x, nullptr, x1b, nullptr, nullptr, 1024, 1024);
    ln_b<<<8192, 256, 0, stream>>>(x1b, ln2g, ln2b, h);
    // FFN1: bias+GELU, 256^2 8-phase counted-vmcnt, 512 blocks
    gemm8<1><<<512, 512, 0, stream>>>(h, wb1, b1, f, nullptr, 4096, 1024);
    // FFN2: out = x1b + f @ w2^T + b2 (fp32 out)
    gemm2p<5><<<256, 512, 0, stream>>>(f, wb2, b2, nullptr, x1b, nullptr, out, nullptr, 1024, 4096);
}

// Round 13
// 403.802 us; speedup vs baseline: 1.0421x; 1.0421x over previous
//
#include <hip/hip_runtime.h>
#include <math.h>

// CLIP transformer layer: B=8 S=1024 D=1024 H=16 DH=64 FF=4096, fp32 I/O,
// bf16 MFMA internals. Round 20: exact revert to the R18 build (412.5us,
// reproduced twice). R19's V LDS-transpose epilogue regressed ~8us (L2
// write-combining was already absorbing the scatter; the transpose added
// barriers + LDS traffic + perturbed all gemm2p instantiations). This is
// the session's best-measured configuration:
//   prep (weights->bf16 + LN1) | QKV gemm2p<3> 768blk | attn balanced 512blk
//   | proj gemm2p<4> | ln_b | FFN1 gemm8<1> 512blk (+free gemm8<3> inst.)
//   | FFN2 gemm2p<5>.

typedef __bf16 bf16_t;
typedef __bf16 bf16x4 __attribute__((ext_vector_type(4)));
typedef __bf16 bf16x8 __attribute__((ext_vector_type(8)));
typedef float f32x4 __attribute__((ext_vector_type(4)));

#define WAITVM(N) asm volatile("s_waitcnt vmcnt(" #N ")" ::: "memory")
#define WAITLGKM0 asm volatile("s_waitcnt lgkmcnt(0)" ::: "memory")
#define SCHEDBAR __builtin_amdgcn_sched_barrier(0)

// ---------------------------------------------------------------- helpers
__device__ __forceinline__ void async16(const void* g, void* l) {
    // global -> LDS direct DMA, 16B/lane. LDS dest is wave-uniform base + lane*16.
    __builtin_amdgcn_global_load_lds(
        (const __attribute__((address_space(1))) void*)g,
        (__attribute__((address_space(3))) void*)l,
        16, 0, 0);
}

__device__ __forceinline__ void ln_row(const float* __restrict__ x,
                                       const float* __restrict__ g,
                                       const float* __restrict__ bb,
                                       bf16_t* __restrict__ out, int row) {
    const int tid = threadIdx.x;
    const float4 xv = *(const float4*)(x + row * 1024 + tid * 4);
    float s1 = xv.x + xv.y + xv.z + xv.w;
    float s2 = xv.x * xv.x + xv.y * xv.y + xv.z * xv.z + xv.w * xv.w;
#pragma unroll
    for (int m = 32; m >= 1; m >>= 1) {
        s1 += __shfl_xor(s1, m);
        s2 += __shfl_xor(s2, m);
    }
    __shared__ float r1[4], r2[4];
    const int wid = tid >> 6, lane = tid & 63;
    if (lane == 0) { r1[wid] = s1; r2[wid] = s2; }
    __syncthreads();
    s1 = r1[0] + r1[1] + r1[2] + r1[3];
    s2 = r2[0] + r2[1] + r2[2] + r2[3];
    const float mu = s1 * (1.0f / 1024.0f);
    const float var = s2 * (1.0f / 1024.0f) - mu * mu;
    const float rs = rsqrtf(var + 1e-5f);
    const float4 gv = *(const float4*)(g + tid * 4);
    const float4 bv = *(const float4*)(bb + tid * 4);
    bf16x4 o;
    o[0] = (bf16_t)((xv.x - mu) * rs * gv.x + bv.x);
    o[1] = (bf16_t)((xv.y - mu) * rs * gv.y + bv.y);
    o[2] = (bf16_t)((xv.z - mu) * rs * gv.z + bv.z);
    o[3] = (bf16_t)((xv.w - mu) * rs * gv.w + bv.w);
    *(bf16x4*)(out + row * 1024 + tid * 4) = o;
}

// ---------------------------------------------------------------- prep: weight converts (blocks 0..12287) + LN1 (blocks 12288..20479)
__global__ __launch_bounds__(256) void prep(
    const float* __restrict__ s0, const float* __restrict__ s1,
    const float* __restrict__ s2, const float* __restrict__ s3,
    bf16_t* __restrict__ d0, bf16_t* __restrict__ d1,
    bf16_t* __restrict__ d2, bf16_t* __restrict__ d3,
    const float* __restrict__ x, const float* __restrict__ ln1g,
    const float* __restrict__ ln1b, bf16_t* __restrict__ h) {
    if (blockIdx.x >= 12288) {
        ln_row(x, ln1g, ln1b, h, blockIdx.x - 12288);
        return;
    }
    const int g = blockIdx.x * 256 + threadIdx.x;  // float4-group index
    const float* s;
    bf16_t* d;
    int off;
    if (g < 786432)       { s = s0; d = d0; off = g; }            // w_qkv 3M elem
    else if (g < 1048576) { s = s1; d = d1; off = g - 786432; }   // w_o 1M
    else if (g < 2097152) { s = s2; d = d2; off = g - 1048576; }  // w1 4M
    else                  { s = s3; d = d3; off = g - 2097152; }  // w2 4M
    const int i = off * 4;
    const float4 v = *(const float4*)(s + i);
    bf16x4 o;
    o[0] = (bf16_t)v.x; o[1] = (bf16_t)v.y; o[2] = (bf16_t)v.z; o[3] = (bf16_t)v.w;
    *(bf16x4*)(d + i) = o;
}

// ---------------------------------------------------------------- LayerNorm over bf16 input (x1 row of 1024) -> bf16
__global__ __launch_bounds__(256) void ln_b(const bf16_t* __restrict__ x,
                                            const float* __restrict__ g,
                                            const float* __restrict__ bb,
                                            bf16_t* __restrict__ out) {
    const int tid = threadIdx.x;
    const int row = blockIdx.x;
    const bf16x4 xb = *(const bf16x4*)(x + row * 1024 + tid * 4);
    const float x0 = (float)xb[0], x1 = (float)xb[1], x2 = (float)xb[2], x3 = (float)xb[3];
    float s1 = x0 + x1 + x2 + x3;
    float s2 = x0 * x0 + x1 * x1 + x2 * x2 + x3 * x3;
#pragma unroll
    for (int m = 32; m >= 1; m >>= 1) {
        s1 += __shfl_xor(s1, m);
        s2 += __shfl_xor(s2, m);
    }
    __shared__ float r1[4], r2[4];
    const int wid = tid >> 6, lane = tid & 63;
    if (lane == 0) { r1[wid] = s1; r2[wid] = s2; }
    __syncthreads();
    s1 = r1[0] + r1[1] + r1[2] + r1[3];
    s2 = r2[0] + r2[1] + r2[2] + r2[3];
    const float mu = s1 * (1.0f / 1024.0f);
    const float var = s2 * (1.0f / 1024.0f) - mu * mu;
    const float rs = rsqrtf(var + 1e-5f);
    const float4 gv = *(const float4*)(g + tid * 4);
    const float4 bv = *(const float4*)(bb + tid * 4);
    bf16x4 o;
    o[0] = (bf16_t)((x0 - mu) * rs * gv.x + bv.x);
    o[1] = (bf16_t)((x1 - mu) * rs * gv.y + bv.y);
    o[2] = (bf16_t)((x2 - mu) * rs * gv.z + bv.z);
    o[3] = (bf16_t)((x3 - mu) * rs * gv.w + bv.w);
    *(bf16x4*)(out + row * 1024 + tid * 4) = o;
}

// ---------------------------------------------------------------- gemm2p: 128x256 tile, 2-phase counted-vmcnt GEMM
// MODE 3: QKV (Q/K -> outb stride N, V -> vt[bh][d][s]);
// MODE 4: bias + fp32 resid -> bf16 (proj); MODE 5: bias + bf16 resid -> fp32 (FFN2).
template <int MODE>
__global__ __launch_bounds__(512, 2) void gemm2p(
    const bf16_t* __restrict__ A, const bf16_t* __restrict__ W,
    const float* __restrict__ bias, const float* __restrict__ residf,
    const bf16_t* __restrict__ residb,
    bf16_t* __restrict__ outb, float* __restrict__ outf,
    bf16_t* __restrict__ vt, int N, int K) {
    __shared__ bf16_t lds[49152];  // 96 KB
    const int tid = threadIdx.x;
    const int w = tid >> 6, lane = tid & 63;
    const int l15 = lane & 15, quad = lane >> 4;
    const int wm = (w & 1) * 64;  // M-offset within 128
    const int wc = w >> 1;        // N-quarter 0..3

    // XCD swizzle (nwg % 8 == 0), then groups of 8 m-blocks per n-column
    const int nwg = gridDim.x;
    const int wg = (blockIdx.x & 7) * (nwg >> 3) + (blockIdx.x >> 3);
    const int nbn = N >> 8;
    const int per = 8 * nbn;
    const int bm = (wg / per) * 8 + (wg % per) % 8;
    const int bn = (wg % per) / 8;
    const int m0 = bm << 7, n0 = bn << 8;

    // staging: A rows 0..127 (2 calls), B rows 0..255 (4 calls); 16B/thread.
    const bf16_t* pa[2]; const bf16_t* pb[4];
#pragma unroll
    for (int L = 0; L < 2; L++) {
        const int c = L * 512 + tid, r = c >> 3;
        pa[L] = A + (size_t)(m0 + r) * K + ((c & 7) ^ (r & 7)) * 8;
    }
#pragma unroll
    for (int L = 0; L < 4; L++) {
        const int c = L * 512 + tid, r = c >> 3;
        pb[L] = W + (size_t)(n0 + r) * K + ((c & 7) ^ (r & 7)) * 8;
    }

    // fragment base pointers (row&7 == l15&7 -> wave-invariant swizzle)
    const int swz0 = (quad ^ (l15 & 7)) * 8;
    const int swz1 = ((4 + quad) ^ (l15 & 7)) * 8;
    const int fragoffA = wm * 64 + l15 * 64 + swz0;
    const bf16_t* bA0 = lds + fragoffA;
    const bf16_t* bA1 = lds + wm * 64 + l15 * 64 + swz1;
    const bf16_t* bB0 = lds + 8192 + wc * 2048 + l15 * 64 + swz0;
    const bf16_t* bB1 = lds + 8192 + wc * 2048 + l15 * 64 + swz1;
    const bf16_t* cA0 = bA0 + 24576;  // twin-buffer pointers
    const bf16_t* cA1 = bA1 + 24576;
    const bf16_t* cB0 = bB0 + 24576;
    const bf16_t* cB1 = bB1 + 24576;

    f32x4 acc[4][4] = {};
    bf16x8 af[4][2], bfr[4][2];

    // prologue: stage tile 0 (A, B-lo, B-hi); publish A+B-lo
    async16(pa[0], lds + w * 512);
    async16(pa[1], lds + 4096 + w * 512);
    async16(pb[0], lds + 8192 + w * 512);
    async16(pb[1], lds + 12288 + w * 512);
    async16(pb[2], lds + 16384 + w * 512);
    async16(pb[3], lds + 20480 + w * 512);
    WAITVM(2);
    __builtin_amdgcn_s_barrier();

    const int NT = K >> 6;
    for (int t = 0; t < NT - 1; ++t) {
        bf16_t* nb = (bf16_t*)(cA0 - fragoffA);  // twin (not-being-read) buffer
        const int kn = (t + 1) << 6;

        // ---- P1: read A + B-lo frags; stage A(t+1) + B-lo(t+1)
#pragma unroll
        for (int i = 0; i < 4; i++) {
            af[i][0] = *(const bf16x8*)(bA0 + i * 1024);
            af[i][1] = *(const bf16x8*)(bA1 + i * 1024);
        }
#pragma unroll
        for (int j = 0; j < 2; j++) {
            bfr[j][0] = *(const bf16x8*)(bB0 + j * 1024);
            bfr[j][1] = *(const bf16x8*)(bB1 + j * 1024);
        }
        async16(pa[0] + kn, nb + w * 512);
        async16(pa[1] + kn, nb + 4096 + w * 512);
        async16(pb[0] + kn, nb + 8192 + w * 512);
        async16(pb[1] + kn, nb + 12288 + w * 512);
        SCHEDBAR;
        __builtin_amdgcn_s_barrier();
        WAITLGKM0;
        SCHEDBAR;
        __builtin_amdgcn_s_setprio(1);
#pragma unroll
        for (int i = 0; i < 4; i++)
#pragma unroll
            for (int j = 0; j < 2; j++)
#pragma unroll
                for (int f = 0; f < 2; f++)
                    acc[i][j] = __builtin_amdgcn_mfma_f32_16x16x32_bf16(af[i][f], bfr[j][f], acc[i][j], 0, 0, 0);
        __builtin_amdgcn_s_setprio(0);
        SCHEDBAR;
        WAITVM(4);  // publish B-hi(t) for P2
        __builtin_amdgcn_s_barrier();

        // ---- P2: read B-hi frags; stage B-hi(t+1)
#pragma unroll
        for (int j = 2; j < 4; j++) {
            bfr[j][0] = *(const bf16x8*)(bB0 + 8192 + (j & 1) * 1024);
            bfr[j][1] = *(const bf16x8*)(bB1 + 8192 + (j & 1) * 1024);
        }
        async16(pb[2] + kn, nb + 16384 + w * 512);
        async16(pb[3] + kn, nb + 20480 + w * 512);
        SCHEDBAR;
        __builtin_amdgcn_s_barrier();
        WAITLGKM0;
        SCHEDBAR;
        __builtin_amdgcn_s_setprio(1);
#pragma unroll
        for (int i = 0; i < 4; i++)
#pragma unroll
            for (int j = 2; j < 4; j++)
#pragma unroll
                for (int f = 0; f < 2; f++)
                    acc[i][j] = __builtin_amdgcn_mfma_f32_16x16x32_bf16(af[i][f], bfr[j][f], acc[i][j], 0, 0, 0);
        __builtin_amdgcn_s_setprio(0);
        SCHEDBAR;
        WAITVM(2);  // publish A(t+1) + B-lo(t+1) for next P1
        __builtin_amdgcn_s_barrier();

        // swap buffer base pointers
        { const bf16_t* s;
          s = bA0; bA0 = cA0; cA0 = s;
          s = bA1; bA1 = cA1; cA1 = s;
          s = bB0; bB0 = cB0; cB0 = s;
          s = bB1; bB1 = cB1; cB1 = s; }
    }

    // peeled last tile: drain 0, no staging
    {
        // P1
#pragma unroll
        for (int i = 0; i < 4; i++) {
            af[i][0] = *(const bf16x8*)(bA0 + i * 1024);
            af[i][1] = *(const bf16x8*)(bA1 + i * 1024);
        }
#pragma unroll
        for (int j = 0; j < 2; j++) {
            bfr[j][0] = *(const bf16x8*)(bB0 + j * 1024);
            bfr[j][1] = *(const bf16x8*)(bB1 + j * 1024);
        }
        SCHEDBAR;
        __builtin_amdgcn_s_barrier();
        WAITLGKM0;
        SCHEDBAR;
        __builtin_amdgcn_s_setprio(1);
#pragma unroll
        for (int i = 0; i < 4; i++)
#pragma unroll
            for (int j = 0; j < 2; j++)
#pragma unroll
                for (int f = 0; f < 2; f++)
                    acc[i][j] = __builtin_amdgcn_mfma_f32_16x16x32_bf16(af[i][f], bfr[j][f], acc[i][j], 0, 0, 0);
        __builtin_amdgcn_s_setprio(0);
        SCHEDBAR;
        WAITVM(0);  // publish B-hi(last)
        __builtin_amdgcn_s_barrier();
        // P2
#pragma unroll
        for (int j = 2; j < 4; j++) {
            bfr[j][0] = *(const bf16x8*)(bB0 + 8192 + (j & 1) * 1024);
            bfr[j][1] = *(const bf16x8*)(bB1 + 8192 + (j & 1) * 1024);
        }
        WAITLGKM0;
        SCHEDBAR;
        __builtin_amdgcn_s_setprio(1);
#pragma unroll
        for (int i = 0; i < 4; i++)
#pragma unroll
            for (int j = 2; j < 4; j++)
#pragma unroll
                for (int f = 0; f < 2; f++)
                    acc[i][j] = __builtin_amdgcn_mfma_f32_16x16x32_bf16(af[i][f], bfr[j][f], acc[i][j], 0, 0, 0);
        __builtin_amdgcn_s_setprio(0);
    }

    // epilogue: C/D layout col=lane&15 (n), row=(lane>>4)*4+reg (m)
#pragma unroll
    for (int i = 0; i < 4; i++) {
        const int row0 = m0 + wm + i * 16 + quad * 4;
#pragma unroll
        for (int j = 0; j < 4; j++) {
            const int col = n0 + (j >> 1) * 128 + wc * 32 + (j & 1) * 16 + l15;
            const float bcol = bias[col];
            if (MODE == 4) {        // + fp32 resid -> bf16 out
#pragma unroll
                for (int q = 0; q < 4; q++) {
                    const size_t idx = (size_t)(row0 + q) * N + col;
                    outb[idx] = (bf16_t)(acc[i][j][q] + bcol + residf[idx]);
                }
            } else if (MODE == 5) { // + bf16 resid -> fp32 out
#pragma unroll
                for (int q = 0; q < 4; q++) {
                    const size_t idx = (size_t)(row0 + q) * N + col;
                    outf[idx] = acc[i][j][q] + bcol + (float)residb[idx];
                }
            } else if (MODE == 3 && col >= 2048) {
                // V column -> vt[bh][d][s]; regs q = 4 consecutive s
                const int bh = (row0 >> 10) * 16 + ((col - 2048) >> 6);
                const int d = (col - 2048) & 63;
                bf16x4 pk;
#pragma unroll
                for (int q = 0; q < 4; q++) pk[q] = (bf16_t)(acc[i][j][q] + bcol);
                *(bf16x4*)(vt + (size_t)bh * 65536 + d * 1024 + (row0 & 1023)) = pk;
            } else {                // MODE 3, Q/K columns
#pragma unroll
                for (int q = 0; q < 4; q++)
                    outb[(size_t)(row0 + q) * N + col] = (bf16_t)(acc[i][j][q] + bcol);
            }
        }
    }
}

// ---------------------------------------------------------------- 256x256 8-phase GEMM, counted vmcnt (round-13, best measured)
// MODE 1: bias+gelu -> bf16 (FFN1); MODE 3 instantiated (not launched) to
// preserve the R13/R15 codegen context in which MODE 1 compiles fast.
template <int MODE>
__global__ __launch_bounds__(512, 2) void gemm8(
    const bf16_t* __restrict__ A, const bf16_t* __restrict__ W,
    const float* __restrict__ bias, bf16_t* __restrict__ outb,
    bf16_t* __restrict__ vt, int N, int K) {
    __shared__ bf16_t lds[65536];  // 128 KB
    const int tid = threadIdx.x;
    const int w = tid >> 6, lane = tid & 63;
    const int l15 = lane & 15, quad = lane >> 4;
    const int wr = w >> 2, wc = w & 3;

    const int nwg = gridDim.x;
    const int wg = (blockIdx.x & 7) * (nwg >> 3) + (blockIdx.x >> 3);
    const int nbn = N >> 8;
    const int per = 8 * nbn;
    const int bm = (wg / per) * 8 + (wg % per) % 8;
    const int bn = (wg % per) / 8;
    const int m0 = bm << 8, n0 = bn << 8;

    int r_[2], s_[2];
#pragma unroll
    for (int L = 0; L < 2; L++) {
        const int c = L * 512 + tid;
        r_[L] = c >> 3;
        s_[L] = ((c & 7) ^ (r_[L] & 7)) * 8;
    }
    const bf16_t* pa0[2]; const bf16_t* pa1[2];
    const bf16_t* pb0[2]; const bf16_t* pb1[2];
#pragma unroll
    for (int L = 0; L < 2; L++) {
        pa0[L] = A + (size_t)(m0 + r_[L]) * K + s_[L];
        pa1[L] = pa0[L] + (size_t)128 * K;
        pb0[L] = W + (size_t)(n0 + r_[L]) * K + s_[L];
        pb1[L] = pb0[L] + (size_t)128 * K;
    }

    const int fragoff = wr * 4096 + l15 * 64;
    const int swz0 = (quad ^ (l15 & 7)) * 8;
    const int swz1 = ((4 + quad) ^ (l15 & 7)) * 8;
    const bf16_t* bA0 = lds + fragoff + swz0;
    const bf16_t* bA1 = lds + fragoff + swz1;
    const bf16_t* bB0 = lds + 16384 + wc * 2048 + l15 * 64 + swz0;
    const bf16_t* bB1 = lds + 16384 + wc * 2048 + l15 * 64 + swz1;
    const bf16_t* cA0 = bA0 + 32768;
    const bf16_t* cA1 = bA1 + 32768;
    const bf16_t* cB0 = bB0 + 32768;
    const bf16_t* cB1 = bB1 + 32768;

    f32x4 acc[8][4] = {};
    bf16x8 af[4][2], bfr[4][2];

    // prologue: stage tile 0 into buf 0 (A-lo, B-lo, B-hi, A-hi);
    // counted wait publishes A-lo+B-lo; B-hi/A-hi stay in flight.
    async16(pa0[0], lds + w * 512);
    async16(pa0[1], lds + 4096 + w * 512);
    async16(pb0[0], lds + 16384 + w * 512);
    async16(pb0[1], lds + 20480 + w * 512);
    async16(pb1[0], lds + 24576 + w * 512);
    async16(pb1[1], lds + 28672 + w * 512);
    async16(pa1[0], lds + 8192 + w * 512);
    async16(pa1[1], lds + 12288 + w * 512);
    WAITVM(4);
    __builtin_amdgcn_s_barrier();

    const int NT = K >> 6;
    for (int t = 0; t < NT - 1; ++t) {
        bf16_t* nb = (bf16_t*)(cA0 - (fragoff + swz0));  // twin buffer
        const int kn = (t + 1) << 6;

        // ---- P1: read af-lo + bf-lo; stage A-lo(t+1)
#pragma unroll
        for (int i = 0; i < 4; i++) {
            af[i][0] = *(const bf16x8*)(bA0 + i * 1024);
            af[i][1] = *(const bf16x8*)(bA1 + i * 1024);
        }
#pragma unroll
        for (int j = 0; j < 2; j++) {
            bfr[j][0] = *(const bf16x8*)(bB0 + j * 1024);
            bfr[j][1] = *(const bf16x8*)(bB1 + j * 1024);
        }
        async16(pa0[0] + kn, nb + w * 512);
        async16(pa0[1] + kn, nb + 4096 + w * 512);
        SCHEDBAR;
        __builtin_amdgcn_s_barrier();
        WAITLGKM0;
        SCHEDBAR;
        __builtin_amdgcn_s_setprio(1);
#pragma unroll
        for (int i = 0; i < 4; i++)
#pragma unroll
            for (int j = 0; j < 2; j++)
#pragma unroll
                for (int f = 0; f < 2; f++)
                    acc[i][j] = __builtin_amdgcn_mfma_f32_16x16x32_bf16(af[i][f], bfr[j][f], acc[i][j], 0, 0, 0);
        __builtin_amdgcn_s_setprio(0);
        SCHEDBAR;
        WAITVM(4);  // publish B-hi(t) for P2
        __builtin_amdgcn_s_barrier();

        // ---- P2: read bf-hi; stage B-lo(t+1)
#pragma unroll
        for (int j = 2; j < 4; j++) {
            bfr[j][0] = *(const bf16x8*)(bB0 + 8192 + (j & 1) * 1024);
            bfr[j][1] = *(const bf16x8*)(bB1 + 8192 + (j & 1) * 1024);
        }
        async16(pb0[0] + kn, nb + 16384 + w * 512);
        async16(pb0[1] + kn, nb + 20480 + w * 512);
        SCHEDBAR;
        __builtin_amdgcn_s_barrier();
        WAITLGKM0;
        SCHEDBAR;
        __builtin_amdgcn_s_setprio(1);
#pragma unroll
        for (int i = 0; i < 4; i++)
#pragma unroll
            for (int j = 2; j < 4; j++)
#pragma unroll
                for (int f = 0; f < 2; f++)
                    acc[i][j] = __builtin_amdgcn_mfma_f32_16x16x32_bf16(af[i][f], bfr[j][f], acc[i][j], 0, 0, 0);
        __builtin_amdgcn_s_setprio(0);
        SCHEDBAR;
        WAITVM(4);  // publish A-hi(t) for P3
        __builtin_amdgcn_s_barrier();

        // ---- P3: read af-hi; stage B-hi(t+1)
#pragma unroll
        for (int i = 0; i < 4; i++) {
            af[i][0] = *(const bf16x8*)(bA0 + 8192 + i * 1024);
            af[i][1] = *(const bf16x8*)(bA1 + 8192 + i * 1024);
        }
        async16(pb1[0] + kn, nb + 24576 + w * 512);
        async16(pb1[1] + kn, nb + 28672 + w * 512);
        SCHEDBAR;
        __builtin_amdgcn_s_barrier();
        WAITLGKM0;
        SCHEDBAR;
        __builtin_amdgcn_s_setprio(1);
#pragma unroll
        for (int i = 0; i < 4; i++)
#pragma unroll
            for (int j = 0; j < 2; j++)
#pragma unroll
                for (int f = 0; f < 2; f++)
                    acc[i + 4][j] = __builtin_amdgcn_mfma_f32_16x16x32_bf16(af[i][f], bfr[j][f], acc[i + 4][j], 0, 0, 0);
        __builtin_amdgcn_s_setprio(0);
        SCHEDBAR;
        __builtin_amdgcn_s_barrier();  // no wait: P4 reads nothing

        // ---- P4: stage A-hi(t+1); MFMA; publish A-lo,B-lo(t+1)
        async16(pa1[0] + kn, nb + 8192 + w * 512);
        async16(pa1[1] + kn, nb + 12288 + w * 512);
        SCHEDBAR;
        __builtin_amdgcn_s_setprio(1);
#pragma unroll
        for (int i = 0; i < 4; i++)
#pragma unroll
            for (int j = 2; j < 4; j++)
#pragma unroll
                for (int f = 0; f < 2; f++)
                    acc[i + 4][j] = __builtin_amdgcn_mfma_f32_16x16x32_bf16(af[i][f], bfr[j][f], acc[i + 4][j], 0, 0, 0);
        __builtin_amdgcn_s_setprio(0);
        SCHEDBAR;
        WAITVM(4);  // publish A-lo,B-lo(t+1) for next P1
        __builtin_amdgcn_s_barrier();

        // swap buffer base pointers
        { const bf16_t* s;
          s = bA0; bA0 = cA0; cA0 = s;
          s = bA1; bA1 = cA1; cA1 = s;
          s = bB0; bB0 = cB0; cB0 = s;
          s = bB1; bB1 = cB1; cB1 = s; }
    }

    // peeled last tile: waits drain 2 -> 0, no staging
    {
        // P1
#pragma unroll
        for (int i = 0; i < 4; i++) {
            af[i][0] = *(const bf16x8*)(bA0 + i * 1024);
            af[i][1] = *(const bf16x8*)(bA1 + i * 1024);
        }
#pragma unroll
        for (int j = 0; j < 2; j++) {
            bfr[j][0] = *(const bf16x8*)(bB0 + j * 1024);
            bfr[j][1] = *(const bf16x8*)(bB1 + j * 1024);
        }
        SCHEDBAR;
        __builtin_amdgcn_s_barrier();
        WAITLGKM0;
        SCHEDBAR;
        __builtin_amdgcn_s_setprio(1);
#pragma unroll
        for (int i = 0; i < 4; i++)
#pragma unroll
            for (int j = 0; j < 2; j++)
#pragma unroll
                for (int f = 0; f < 2; f++)
                    acc[i][j] = __builtin_amdgcn_mfma_f32_16x16x32_bf16(af[i][f], bfr[j][f], acc[i][j], 0, 0, 0);
        __builtin_amdgcn_s_setprio(0);
        SCHEDBAR;
        WAITVM(2);  // publish B-hi(last)
        __builtin_amdgcn_s_barrier();
        // P2
#pragma unroll
        for (int j = 2; j < 4; j++) {
            bfr[j][0] = *(const bf16x8*)(bB0 + 8192 + (j & 1) * 1024);
            bfr[j][1] = *(const bf16x8*)(bB1 + 8192 + (j & 1) * 1024);
        }
        SCHEDBAR;
        __builtin_amdgcn_s_barrier();
        WAITLGKM0;
        SCHEDBAR;
        __builtin_amdgcn_s_setprio(1);
#pragma unroll
        for (int i = 0; i < 4; i++)
#pragma unroll
            for (int j = 2; j < 4; j++)
#pragma unroll
                for (int f = 0; f < 2; f++)
                    acc[i][j] = __builtin_amdgcn_mfma_f32_16x16x32_bf16(af[i][f], bfr[j][f], acc[i][j], 0, 0, 0);
        __builtin_amdgcn_s_setprio(0);
        SCHEDBAR;
        WAITVM(0);  // publish A-hi(last)
        __builtin_amdgcn_s_barrier();
        // P3 + P4
#pragma unroll
        for (int i = 0; i < 4; i++) {
            af[i][0] = *(const bf16x8*)(bA0 + 8192 + i * 1024);
            af[i][1] = *(const bf16x8*)(bA1 + 8192 + i * 1024);
        }
        WAITLGKM0;
        SCHEDBAR;
        __builtin_amdgcn_s_setprio(1);
#pragma unroll
        for (int i = 0; i < 4; i++)
#pragma unroll
            for (int j = 0; j < 4; j++)
#pragma unroll
                for (int f = 0; f < 2; f++)
                    acc[i + 4][j] = __builtin_amdgcn_mfma_f32_16x16x32_bf16(af[i][f], bfr[j][f], acc[i + 4][j], 0, 0, 0);
        __builtin_amdgcn_s_setprio(0);
    }

    // epilogue
#pragma unroll
    for (int i = 0; i < 8; i++) {
        const int row0 = m0 + (i >> 2) * 128 + wr * 64 + (i & 3) * 16 + quad * 4;
#pragma unroll
        for (int j = 0; j < 4; j++) {
            const int col = n0 + (j >> 1) * 128 + wc * 32 + (j & 1) * 16 + l15;
            const float bcol = bias[col];
            float v4[4];
#pragma unroll
            for (int q = 0; q < 4; q++) {
                float v = acc[i][j][q] + bcol;
                if (MODE == 1) {  // tanh-GELU == x * sigmoid(2u)
                    const float u2 = -1.5957691216057308f * (v + 0.044715f * v * v * v);
                    v = v * __builtin_amdgcn_rcpf(1.0f + __expf(u2));
                }
                v4[q] = v;
            }
            if (MODE == 3 && col >= 2048) {
                const int bh = (row0 >> 10) * 16 + ((col - 2048) >> 6);
                const int d = (col - 2048) & 63;
                bf16x4 pk;
#pragma unroll
                for (int q = 0; q < 4; q++) pk[q] = (bf16_t)v4[q];
                *(bf16x4*)(vt + (size_t)bh * 65536 + d * 1024 + (row0 & 1023)) = pk;
            } else {
#pragma unroll
                for (int q = 0; q < 4; q++)
                    outb[(size_t)(row0 + q) * N + col] = (bf16_t)v4[q];
            }
        }
    }
}

// Explicit instantiation of gemm8<3> (never launched): preserves the
// R13/R15 module codegen context for gemm8<1>. Rule #19.
template __global__ void gemm8<3>(const bf16_t*, const bf16_t*, const float*,
                                  bf16_t*, bf16_t*, int, int);

// ---------------------------------------------------------------- MFMA causal flash attention, K/V double-buffered, balanced grid
// 512 1-D blocks, 512 thr = 8 waves; wave owns 32 queries (two 16-q groups).
// Complementary-qb pairing: beta<256 -> (qb=beta&3, bh=beta>>2); beta>=256
// -> (qb=3-(beta-256)&3, bh=64+(beta-256)>>2). Blocks beta and beta+256
// land on the same CU (round-robin) and their causal work sums to a
// constant 20 tile-units. bh-locality preserved.
__global__ __launch_bounds__(512) void attn_mfma(const bf16_t* __restrict__ qkv,
                                                 const bf16_t* __restrict__ vt,
                                                 bf16_t* __restrict__ o) {
    __shared__ bf16_t Ks[2][4096];    // [buf][key=64][dseg swizzled] 16KB
    __shared__ bf16_t Vs[2][4096];    // [buf][d=64][kseg swizzled]   16KB
    __shared__ bf16_t Ps[8][16][72];  // per-wave P[q(16)][key], pad 72 (18KB)
    const int tid = threadIdx.x;
    const int w = tid >> 6;           // 0..7
    const int lane = tid & 63;
    const int l15 = lane & 15;
    const int quad = lane >> 4;
    const int beta = blockIdx.x;      // 0..511
    int qb, bh;
    if (beta < 256) { qb = beta & 3; bh = beta >> 2; }
    else { const int gm = beta - 256; qb = 3 - (gm & 3); bh = 64 + (gm >> 2); }
    const int b = bh >> 4, h = bh & 15;

    const int qrow = b * 1024 + qb * 256 + w * 32;  // wave's first query row (global)

    // Q^T B-frags for both 16-q groups, scaled by 1/8 (exact pow2)
    bf16x8 qf[2][2];
#pragma unroll
    for (int g = 0; g < 2; g++)
#pragma unroll
        for (int f = 0; f < 2; f++) {
            bf16x8 t = *(const bf16x8*)(qkv + (size_t)(qrow + g * 16 + l15) * 3072 + h * 64 + f * 32 + quad * 8);
#pragma unroll
            for (int e = 0; e < 8; e++) t[e] = (bf16_t)((float)t[e] * 0.125f);
            qf[g][f] = t;
        }

    f32x4 Ot[2][4] = {};
    float mrow[2] = {-3.0e38f, -3.0e38f};
    float lrow[2] = {0.0f, 0.0f};

    // staging: 1 call/wave per operand; chunk c = w*64 + lane (16B each)
    const int c0 = w * 64 + lane;
    const int r0 = c0 >> 3, g0 = (((c0 & 7) ^ (r0 & 7))) * 8;

    const bf16_t* kbase = qkv + (size_t)(b * 1024) * 3072 + 1024 + h * 64;
    const bf16_t* vbase = vt + (size_t)bh * 64 * 1024;

    const int ktmax = 4 * qb + 3;  // keys up to qb*256+255

    // prologue: stage tile 0 into buf 0, full publish
    async16(kbase + (size_t)r0 * 3072 + g0, &Ks[0][0] + w * 512);
    async16(vbase + (size_t)r0 * 1024 + g0, &Vs[0][0] + w * 512);
    WAITVM(0);
    __builtin_amdgcn_s_barrier();

    int p = 0;
    for (int kt = 0; kt <= ktmax; kt++, p ^= 1) {
        // issue-early: stage tile kt+1 into the twin buffer (race-free:
        // its last reads finished before the previous iteration's barrier)
        if (kt < ktmax) {
            async16(kbase + (size_t)((kt + 1) * 64 + r0) * 3072 + g0, &Ks[p ^ 1][0] + w * 512);
            async16(vbase + (size_t)r0 * 1024 + (kt + 1) * 64 + g0, &Vs[p ^ 1][0] + w * 512);
        }
        const bf16_t* Kp = &Ks[p][0];
        const bf16_t* Vp = &Vs[p][0];

#pragma unroll
        for (int g = 0; g < 2; g++) {
            const int qmaxw = qb * 256 + w * 32 + g * 16 + 15;  // group's max query
            if (kt * 64 > qmaxw) continue;  // whole tile masked for this group
            const int ktd = qmaxw >> 6;     // diagonal tile
            const int kbd = (2 * w + g) & 3;

            f32x4 sf[4];
#pragma unroll
            for (int kb = 0; kb < 4; kb++) {
                if (kt * 64 + kb * 16 > qmaxw) {  // fully masked key-block
                    sf[kb] = (f32x4){-3.0e38f, -3.0e38f, -3.0e38f, -3.0e38f};
                    continue;
                }
                const int r = kb * 16 + l15;
                f32x4 acc = {};
#pragma unroll
                for (int f = 0; f < 2; f++) {
                    const int seg = (f * 4 + quad) ^ (r & 7);
                    const bf16x8 kf = *(const bf16x8*)(Kp + r * 64 + seg * 8);
                    acc = __builtin_amdgcn_mfma_f32_16x16x32_bf16(kf, qf[g][f], acc, 0, 0, 0);
                }
                if (kt == ktd && kb == kbd) {  // diagonal 16-block: per-element mask
#pragma unroll
                    for (int rr2 = 0; rr2 < 4; rr2++)
                        if (quad * 4 + rr2 > l15) acc[rr2] = -3.0e38f;
                }
                sf[kb] = acc;
            }

            // online softmax over columns (q = l15)
            float tmax = -3.0e38f;
#pragma unroll
            for (int kb = 0; kb < 4; kb++)
#pragma unroll
                for (int rr2 = 0; rr2 < 4; rr2++) tmax = fmaxf(tmax, sf[kb][rr2]);
            tmax = fmaxf(tmax, __shfl_xor(tmax, 16));
            tmax = fmaxf(tmax, __shfl_xor(tmax, 32));
            const float mnew = fmaxf(mrow[g], tmax);
            const float alpha = __expf(mrow[g] - mnew);
            float psum = 0.0f;
#pragma unroll
            for (int kb = 0; kb < 4; kb++) {
                bf16x4 pk;
#pragma unroll
                for (int rr2 = 0; rr2 < 4; rr2++) {
                    const float p2 = __expf(sf[kb][rr2] - mnew);
                    psum += p2;
                    pk[rr2] = (bf16_t)p2;
                }
                *(bf16x4*)(&Ps[w][l15][kb * 16 + quad * 4]) = pk;
            }
            psum += __shfl_xor(psum, 16);
            psum += __shfl_xor(psum, 32);
            lrow[g] = lrow[g] * alpha + psum;
            mrow[g] = mnew;
#pragma unroll
            for (int db = 0; db < 4; db++)
#pragma unroll
                for (int rr2 = 0; rr2 < 4; rr2++) Ot[g][db][rr2] *= alpha;

#pragma unroll
            for (int ks = 0; ks < 2; ks++) {
                if (kt * 64 + ks * 32 > qmaxw) break;  // all-zero P (wave-uniform)
                const bf16x8 pf = *(const bf16x8*)(&Ps[w][l15][ks * 32 + quad * 8]);
#pragma unroll
                for (int db = 0; db < 4; db++) {
                    const int d = db * 16 + l15;
                    const int seg = (ks * 4 + quad) ^ (d & 7);
                    const bf16x8 vf = *(const bf16x8*)(Vp + d * 64 + seg * 8);
                    Ot[g][db] = __builtin_amdgcn_mfma_f32_16x16x32_bf16(vf, pf, Ot[g][db], 0, 0, 0);
                }
            }
        }
        SCHEDBAR;
        WAITVM(0);  // kt+1's loads issued before compute: drain ~free
        __builtin_amdgcn_s_barrier();
    }

#pragma unroll
    for (int g = 0; g < 2; g++) {
        const float rl = 1.0f / lrow[g];
#pragma unroll
        for (int db = 0; db < 4; db++) {
            bf16x4 ov;
#pragma unroll
            for (int rr2 = 0; rr2 < 4; rr2++) ov[rr2] = (bf16_t)(Ot[g][db][rr2] * rl);
            *(bf16x4*)(o + (size_t)(qrow + g * 16 + l15) * 1024 + h * 64 + db * 16 + quad * 4) = ov;
        }
    }
}

// ---------------------------------------------------------------- launch
extern "C" void kernel_launch(void* const* d_in, const int* in_sizes, int n_in,
                              void* d_out, int out_size, void* d_ws, size_t ws_size,
                              hipStream_t stream) {
    const float* x     = (const float*)d_in[0];
    const float* ln1g  = (const float*)d_in[1];
    const float* ln1b  = (const float*)d_in[2];
    const float* w_qkv = (const float*)d_in[3];
    const float* b_qkv = (const float*)d_in[4];
    const float* w_o   = (const float*)d_in[5];
    const float* b_o   = (const float*)d_in[6];
    const float* ln2g  = (const float*)d_in[7];
    const float* ln2b  = (const float*)d_in[8];
    const float* w1    = (const float*)d_in[9];
    const float* b1    = (const float*)d_in[10];
    const float* w2    = (const float*)d_in[11];
    const float* b2    = (const float*)d_in[12];
    float* out = (float*)d_out;

    char* w = (char*)d_ws;
    bf16_t* wbqkv = (bf16_t*)(w + 0);          //  6 MB  [3072,1024] bf16
    bf16_t* wbo   = (bf16_t*)(w + 6291456);    //  2 MB  [1024,1024]
    bf16_t* wb1   = (bf16_t*)(w + 8388608);    //  8 MB  [4096,1024]
    bf16_t* wb2   = (bf16_t*)(w + 16777216);   //  8 MB  [1024,4096]
    bf16_t* h     = (bf16_t*)(w + 25165824);   // 16 MB  [8192,1024] (LN1/LN2 out)
    bf16_t* qkv   = (bf16_t*)(w + 41943040);   // 48 MB  [8192,3072] (V region unused)
    bf16_t* ob    = (bf16_t*)(w + 92274688);   // 16 MB  [8192,1024]
    bf16_t* x1b   = (bf16_t*)(w + 109051904);  // 16 MB  [8192,1024] bf16 residual stream
    bf16_t* f     = (bf16_t*)(w + 142606336);  // 64 MB  [8192,4096] (FFN1 out)
    bf16_t* vtb   = (bf16_t*)(w + 142606336);  // 16 MB  [128][64][1024] (aliases f; dead before FFN1)

    // weight converts + LN1 in one dispatch
    prep<<<20480, 256, 0, stream>>>(w_qkv, w_o, w1, w2, wbqkv, wbo, wb1, wb2,
                                    x, ln1g, ln1b, h);
    // QKV: 128x256 2-phase counted-vmcnt, 768 blocks = 3 exact rounds
    gemm2p<3><<<768, 512, 0, stream>>>(h, wbqkv, b_qkv, nullptr, nullptr, qkv, nullptr, vtb, 3072, 1024);
    // attention: balanced 1-D grid (complementary-qb pairing)
    attn_mfma<<<512, 512, 0, stream>>>(qkv, vtb, ob);
    // proj: x1b = bf16(x + ob @ w_o^T + b_o)
    gemm2p<4><<<256, 512, 0, stream>>>(ob, wbo, b_o, x, nullptr, x1b, nullptr, nullptr, 1024, 1024);
    ln_b<<<8192, 256, 0, stream>>>(x1b, ln2g, ln2b, h);
    // FFN1: bias+GELU, 256^2 8-phase counted-vmcnt, 512 blocks
    gemm8<1><<<512, 512, 0, stream>>>(h, wb1, b1, f, nullptr, 4096, 1024);
    // FFN2: out = x1b + f @ w2^T + b2 (fp32 out)
    gemm2p<5><<<256, 512, 0, stream>>>(f, wb2, b2, nullptr, x1b, nullptr, out, nullptr, 1024, 4096);
}